// Round 2
// baseline (696.803 us; speedup 1.0000x reference)
//
#include <hip/hip_runtime.h>
#include <hip/hip_bf16.h>

typedef __bf16 bf16x8 __attribute__((ext_vector_type(8)));
typedef __bf16 bf16x4 __attribute__((ext_vector_type(4)));
typedef float  f32x4  __attribute__((ext_vector_type(4)));

#define MFMA16(a, b, c) __builtin_amdgcn_mfma_f32_16x16x32_bf16((a), (b), (c), 0, 0, 0)

// ---------------------------------------------------------------------------
// K1: block 240: exclusive scan of sizes; blocks 0-47: conv weight pack;
// blocks 48-239: lin_w hi/lo pack.
// B-frag for 16x16x32: lane holds B[k = (lane>>4)*8 + j][n = lane&15], j=0..7.
// ---------------------------------------------------------------------------
__global__ void k_prep(const int* __restrict__ sizes, int* __restrict__ offsets,
                       const float* __restrict__ w0, const float* __restrict__ w1,
                       const float* __restrict__ w2, const float* __restrict__ lw,
                       __bf16* __restrict__ Wpack,
                       __bf16* __restrict__ Lhi, __bf16* __restrict__ Llo) {
  const int bid = blockIdx.x, t = threadIdx.x;
  if (bid == 240) {
    __shared__ int part[256];
    const int base = t * 32;
    int v[32];
    int s = 0;
#pragma unroll
    for (int i = 0; i < 32; ++i) { v[i] = sizes[base + i]; s += v[i]; }
    part[t] = s;
    __syncthreads();
    for (int d = 1; d < 256; d <<= 1) {
      int add = (t >= d) ? part[t - d] : 0;
      __syncthreads();
      part[t] += add;
      __syncthreads();
    }
    int run = (t == 0) ? 0 : part[t - 1];
#pragma unroll
    for (int i = 0; i < 32; ++i) { offsets[base + i] = run; run += v[i]; }
  } else if (bid < 48) {
    const int nt = bid, sl = nt >> 3, f = nt & 7;
    const int kt = t >> 6, lane = t & 63;
    const float* src; int kw, jj;
    if      (sl == 0) { src = w0; kw = 1; jj = 0; }
    else if (sl == 1) { src = w1; kw = 2; jj = 0; }
    else if (sl == 2) { src = w1; kw = 2; jj = 1; }
    else if (sl == 3) { src = w2; kw = 3; jj = 0; }
    else if (sl == 4) { src = w2; kw = 3; jj = 1; }
    else              { src = w2; kw = 3; jj = 2; }
    const int feat  = f * 16 + (lane & 15);
    const int cbase = kt * 32 + ((lane >> 4) << 3);
    __bf16* dst = Wpack + ((((nt * 4 + kt) << 6) + lane) << 3);
#pragma unroll
    for (int j = 0; j < 8; ++j)
      dst[j] = (__bf16)src[(feat * 128 + cbase + j) * kw + jj];
  } else {
    const int idx = (bid - 48) * 256 + t;          // 0..49151
    const int j = idx & 7, lane = (idx >> 3) & 63, rest = idx >> 9;  // 0..95
    const int kt = rest % 12, nt = rest / 12;
    const int o = nt * 16 + (lane & 15);
    const int q = kt * 32 + ((lane >> 4) << 3) + j;
    const float v = lw[o * 384 + q];
    const __bf16 hi = (__bf16)v;
    Lhi[idx] = hi;
    Llo[idx] = (__bf16)(v - (float)hi);
  }
}

// ---------------------------------------------------------------------------
// K2 v3: 512 blocks x 512 threads, SPB=16, __launch_bounds__(512,4):
// 2 independent blocks per CU (16 waves/CU, 4/SIMD) so one block's barrier/
// vmcnt drain hides under the other's MFMAs.  Weights re-loaded per kt (L1-hot
// same-address) to stay <=128 VGPR.  No zero-padding: garbage rows >= s feed
// only predicate-masked outputs (valid row p < s-w+1 reads rows <= s-1), so
// staging is exactly s*16 granules (<=1024 -> 2 per thread).
// LDS: row-major [row][128] bf16, granule g at g^(row&7): staging writes and
// 3-tap ds_read_b128 both <=2-way (free).
// C/D layout (m89-verified): col = lane&15, row = (lane>>4)*4 + reg.
// ---------------------------------------------------------------------------
#define SPB 16   // segments per block: 8192 / 512

__global__ __launch_bounds__(512, 4)
void k_conv(const float* __restrict__ x, const int* __restrict__ sizes,
            const int* __restrict__ offsets,
            const float* __restrict__ cb0, const float* __restrict__ cb1,
            const float* __restrict__ cb2,
            const bf16x8* __restrict__ Wpack,
            __bf16* __restrict__ Phi, __bf16* __restrict__ Plo) {
  __shared__ __align__(16) __bf16 xs[2][66 * 128];   // 2 x 16.5 KB
  const int t = threadIdx.x;
  const int wid = t >> 6, lane = t & 63;
  const int lo16 = lane & 15, g16 = lane >> 4;
  // swizzle keys per tap: (mt*16)&7 == 0, so row&7 depends only on lo16+tap
  const int xr0 = lo16 & 7, xr1 = (lo16 + 1) & 7, xr2 = (lo16 + 2) & 7;
  const int seg0 = blockIdx.x * SPB;

  int s_cur = sizes[seg0];
  // --- prologue: stage segment seg0 into xs[0] (rows [0,s) only) ---
  {
    const long o_cur = offsets[seg0];
    const int uend = s_cur << 4;
#pragma unroll
    for (int k = 0; k < 2; ++k) {
      const int u = t + (k << 9);
      if (u < uend) {
        const int r = u >> 4, g = u & 15;
        const float* p = x + (o_cur + r) * 128 + (g << 3);
        const float4 a = *(const float4*)p;
        const float4 b = *(const float4*)(p + 4);
        bf16x8 h;
        h[0] = (__bf16)a.x; h[1] = (__bf16)a.y; h[2] = (__bf16)a.z; h[3] = (__bf16)a.w;
        h[4] = (__bf16)b.x; h[5] = (__bf16)b.y; h[6] = (__bf16)b.z; h[7] = (__bf16)b.w;
        *(bf16x8*)&xs[0][r * 128 + ((g ^ (r & 7)) << 3)] = h;
      }
    }
  }
  __syncthreads();

  int cur = 0;
  int s_nn = sizes[seg0 + 1];     // descriptor prefetch, one iter ahead
  int o_nn = offsets[seg0 + 1];

  for (int i = 0; i < SPB; ++i) {
    const int seg = seg0 + i;
    const int s = s_cur;
    const int MT = (s + 15) >> 4;     // 1..4, block-uniform

    // ---- phase A: issue next segment's global loads (regs only) ----
    const int s_nxt = s_nn;
    const long o_nxt = (long)o_nn;
    float4 va0, vb0, va1, vb1;
    bool a0 = false, a1 = false;
    if (i + 1 < SPB) {
      const int uend = s_nxt << 4;
      {
        a0 = t < uend;
        if (a0) {
          const int r = t >> 4, g = t & 15;
          const float* p = x + (o_nxt + r) * 128 + (g << 3);
          va0 = *(const float4*)p; vb0 = *(const float4*)(p + 4);
        }
      }
      {
        const int u = t + 512;
        a1 = u < uend;
        if (a1) {
          const int r = u >> 4, g = u & 15;
          const float* p = x + (o_nxt + r) * 128 + (g << 3);
          va1 = *(const float4*)p; vb1 = *(const float4*)(p + 4);
        }
      }
      if (i + 2 < SPB) { s_nn = sizes[seg + 2]; o_nn = offsets[seg + 2]; }
    }

    // ---- phase B: MFMA from xs[cur]; weights per-kt from L1-hot Wpack ----
    f32x4 acc[4][3];
#pragma unroll
    for (int mt = 0; mt < 4; ++mt)
#pragma unroll
      for (int p = 0; p < 3; ++p)
        acc[mt][p] = f32x4{0.f, 0.f, 0.f, 0.f};

    const __bf16* xb = xs[cur];
#pragma unroll
    for (int kt = 0; kt < 4; ++kt) {
      bf16x8 bf[6];
#pragma unroll
      for (int sl = 0; sl < 6; ++sl)
        bf[sl] = Wpack[(((sl * 8 + wid) * 4 + kt) << 6) + lane];
      const int gg = kt * 4 + g16;
      const int c0 = (gg ^ xr0) << 3, c1 = (gg ^ xr1) << 3, c2 = (gg ^ xr2) << 3;
#pragma unroll
      for (int mt = 0; mt < 4; ++mt) {
        if (mt < MT) {              // uniform per block
          const int rb = (mt * 16 + lo16) * 128;
          const bf16x8 A0 = *(const bf16x8*)&xb[rb + c0];
          const bf16x8 A1 = *(const bf16x8*)&xb[rb + 128 + c1];
          const bf16x8 A2 = *(const bf16x8*)&xb[rb + 256 + c2];
          acc[mt][0] = MFMA16(A0, bf[0], acc[mt][0]);
          acc[mt][1] = MFMA16(A0, bf[1], acc[mt][1]);
          acc[mt][2] = MFMA16(A0, bf[3], acc[mt][2]);
          acc[mt][1] = MFMA16(A1, bf[2], acc[mt][1]);
          acc[mt][2] = MFMA16(A1, bf[4], acc[mt][2]);
          acc[mt][2] = MFMA16(A2, bf[5], acc[mt][2]);
        }
      }
    }

    // ---- phase C: write staged regs into xs[cur^1] (loads landed under B) ----
    if (i + 1 < SPB) {
      if (a0) {
        const int r = t >> 4, g = t & 15;
        bf16x8 h;
        h[0] = (__bf16)va0.x; h[1] = (__bf16)va0.y; h[2] = (__bf16)va0.z; h[3] = (__bf16)va0.w;
        h[4] = (__bf16)vb0.x; h[5] = (__bf16)vb0.y; h[6] = (__bf16)vb0.z; h[7] = (__bf16)vb0.w;
        *(bf16x8*)&xs[cur ^ 1][r * 128 + ((g ^ (r & 7)) << 3)] = h;
      }
      if (a1) {
        const int u = t + 512;
        const int r = u >> 4, g = u & 15;
        bf16x8 h;
        h[0] = (__bf16)va1.x; h[1] = (__bf16)va1.y; h[2] = (__bf16)va1.z; h[3] = (__bf16)va1.w;
        h[4] = (__bf16)vb1.x; h[5] = (__bf16)vb1.y; h[6] = (__bf16)vb1.z; h[7] = (__bf16)vb1.w;
        *(bf16x8*)&xs[cur ^ 1][r * 128 + ((g ^ (r & 7)) << 3)] = h;
      }
    }

    // ---- epilogue: predicated max over valid rows, butterfly, store ----
    float m1 = -3e38f, m2 = -3e38f, m3 = -3e38f;
#pragma unroll
    for (int mt = 0; mt < 4; ++mt) {
      if (mt < MT) {
#pragma unroll
        for (int v = 0; v < 4; ++v) {
          const int lrow = mt * 16 + g16 * 4 + v;
          if (lrow < s)     m1 = fmaxf(m1, acc[mt][0][v]);
          if (lrow < s - 1) m2 = fmaxf(m2, acc[mt][1][v]);
          if (lrow < s - 2) m3 = fmaxf(m3, acc[mt][2][v]);
        }
      }
    }
    m1 = fmaxf(m1, __shfl_xor(m1, 16)); m1 = fmaxf(m1, __shfl_xor(m1, 32));
    m2 = fmaxf(m2, __shfl_xor(m2, 16)); m2 = fmaxf(m2, __shfl_xor(m2, 32));
    m3 = fmaxf(m3, __shfl_xor(m3, 16)); m3 = fmaxf(m3, __shfl_xor(m3, 32));
    if (g16 == 0) {
      const int feat = wid * 16 + lo16;
      // max(relu(h)) == relu(max(Y)+b): bias row-constant, relu monotone
      const float p1 = fmaxf(m1 + cb0[feat], 0.f);
      const float p2 = fmaxf(m2 + cb1[feat], 0.f);
      const float p3 = fmaxf(m3 + cb2[feat], 0.f);
      const __bf16 h1 = (__bf16)p1, h2 = (__bf16)p2, h3 = (__bf16)p3;
      const long row = (long)seg * 384;
      Phi[row + feat]       = h1;
      Plo[row + feat]       = (__bf16)(p1 - (float)h1);
      Phi[row + 128 + feat] = h2;
      Plo[row + 128 + feat] = (__bf16)(p2 - (float)h2);
      Phi[row + 256 + feat] = h3;
      Plo[row + 256 + feat] = (__bf16)(p3 - (float)h3);
    }

    __syncthreads();
    s_cur = s_nxt;
    cur ^= 1;
  }
}

// ---------------------------------------------------------------------------
// K3: out = tanh(P[8192,384] @ lin_w^T + lin_b), split bf16 MFMA (3 products:
// Ph*Wh + Pl*Wh + Ph*Wl -> ~fp32 accuracy).  512 blocks x 16 batch rows.
// ---------------------------------------------------------------------------
__global__ __launch_bounds__(256, 4)
void k_lin(const __bf16* __restrict__ Phi, const __bf16* __restrict__ Plo,
           const bf16x8* __restrict__ Lhi, const bf16x8* __restrict__ Llo,
           const float* __restrict__ lb, float* __restrict__ out) {
  __shared__ __bf16 ph[16 * 392];   // [row][384 + 8 pad]
  __shared__ __bf16 pl[16 * 392];
  const int blk = blockIdx.x, t = threadIdx.x;
  const long rbase = (long)blk * 16;
#pragma unroll
  for (int i = 0; i < 3; ++i) {
    const int ci = t + (i << 8);
    const int r = ci / 48, cc = ci % 48;
    *(int4*)&ph[r * 392 + (cc << 3)] = *(const int4*)&Phi[(rbase + r) * 384 + (cc << 3)];
    *(int4*)&pl[r * 392 + (cc << 3)] = *(const int4*)&Plo[(rbase + r) * 384 + (cc << 3)];
  }
  __syncthreads();
  const int wid = t >> 6, lane = t & 63;
  const int lo16 = lane & 15, g = lane >> 4;
#pragma unroll
  for (int ni = 0; ni < 2; ++ni) {
    const int nt = wid + (ni << 2);
    f32x4 acc = f32x4{0.f, 0.f, 0.f, 0.f};
#pragma unroll
    for (int kt = 0; kt < 12; ++kt) {
      const bf16x8 bh = Lhi[((nt * 12 + kt) << 6) + lane];
      const bf16x8 bl = Llo[((nt * 12 + kt) << 6) + lane];
      const int aoff = lo16 * 392 + kt * 32 + (g << 3);
      const bf16x8 ah = *(const bf16x8*)&ph[aoff];
      const bf16x8 al = *(const bf16x8*)&pl[aoff];
      acc = MFMA16(ah, bh, acc);
      acc = MFMA16(al, bh, acc);
      acc = MFMA16(ah, bl, acc);
    }
    const int o = nt * 16 + lo16;
    const float bias = lb[o];
#pragma unroll
    for (int v = 0; v < 4; ++v) {
      const int r = g * 4 + v;
      const float val = acc[v] + bias;
      out[(rbase + r) * 128 + o] = 1.f - 2.f / (__expf(2.f * val) + 1.f);
    }
  }
}

// ---------------------------------------------------------------------------
extern "C" void kernel_launch(void* const* d_in, const int* in_sizes, int n_in,
                              void* d_out, int out_size, void* d_ws, size_t ws_size,
                              hipStream_t stream) {
  const float* x   = (const float*)d_in[0];
  const int* sizes = (const int*)d_in[1];
  const float* w0  = (const float*)d_in[2];
  const float* cb0 = (const float*)d_in[3];
  const float* w1  = (const float*)d_in[4];
  const float* cb1 = (const float*)d_in[5];
  const float* w2  = (const float*)d_in[6];
  const float* cb2 = (const float*)d_in[7];
  const float* lw  = (const float*)d_in[8];
  const float* lb  = (const float*)d_in[9];

  char* ws = (char*)d_ws;
  size_t o = 0;
  int*    offsets = (int*)ws;                 o += 32768;
  __bf16* Wpack   = (__bf16*)(ws + o);        o += 196608;     // 48*4*64*8*2
  __bf16* Lhi     = (__bf16*)(ws + o);        o += 98304;      // 8*12*64*8*2
  __bf16* Llo     = (__bf16*)(ws + o);        o += 98304;
  __bf16* Phi     = (__bf16*)(ws + o);        o += 8192L * 384 * 2;
  __bf16* Plo     = (__bf16*)(ws + o);        o += 8192L * 384 * 2;

  k_prep<<<241, 256, 0, stream>>>(sizes, offsets, w0, w1, w2, lw, Wpack, Lhi, Llo);
  k_conv<<<512, 512, 0, stream>>>(x, sizes, offsets, cb0, cb1, cb2,
                                  (const bf16x8*)Wpack, Phi, Plo);
  k_lin<<<512, 256, 0, stream>>>(Phi, Plo, (const bf16x8*)Lhi,
                                 (const bf16x8*)Llo, lb, (float*)d_out);
}

// Round 3
// 324.979 us; speedup vs baseline: 2.1442x; 2.1442x over previous
//
#include <hip/hip_runtime.h>
#include <hip/hip_bf16.h>

typedef __bf16 bf16x8 __attribute__((ext_vector_type(8)));
typedef __bf16 bf16x4 __attribute__((ext_vector_type(4)));
typedef float  f32x4  __attribute__((ext_vector_type(4)));

#define MFMA16(a, b, c) __builtin_amdgcn_mfma_f32_16x16x32_bf16((a), (b), (c), 0, 0, 0)

// ---------------------------------------------------------------------------
// K1: block 240: exclusive scan of sizes; blocks 0-47: conv weight pack;
// blocks 48-239: lin_w hi/lo pack.
// B-frag for 16x16x32: lane holds B[k = (lane>>4)*8 + j][n = lane&15], j=0..7.
// ---------------------------------------------------------------------------
__global__ void k_prep(const int* __restrict__ sizes, int* __restrict__ offsets,
                       const float* __restrict__ w0, const float* __restrict__ w1,
                       const float* __restrict__ w2, const float* __restrict__ lw,
                       __bf16* __restrict__ Wpack,
                       __bf16* __restrict__ Lhi, __bf16* __restrict__ Llo) {
  const int bid = blockIdx.x, t = threadIdx.x;
  if (bid == 240) {
    __shared__ int part[256];
    const int base = t * 32;
    int v[32];
    int s = 0;
#pragma unroll
    for (int i = 0; i < 32; ++i) { v[i] = sizes[base + i]; s += v[i]; }
    part[t] = s;
    __syncthreads();
    for (int d = 1; d < 256; d <<= 1) {
      int add = (t >= d) ? part[t - d] : 0;
      __syncthreads();
      part[t] += add;
      __syncthreads();
    }
    int run = (t == 0) ? 0 : part[t - 1];
#pragma unroll
    for (int i = 0; i < 32; ++i) { offsets[base + i] = run; run += v[i]; }
  } else if (bid < 48) {
    const int nt = bid, sl = nt >> 3, f = nt & 7;
    const int kt = t >> 6, lane = t & 63;
    const float* src; int kw, jj;
    if      (sl == 0) { src = w0; kw = 1; jj = 0; }
    else if (sl == 1) { src = w1; kw = 2; jj = 0; }
    else if (sl == 2) { src = w1; kw = 2; jj = 1; }
    else if (sl == 3) { src = w2; kw = 3; jj = 0; }
    else if (sl == 4) { src = w2; kw = 3; jj = 1; }
    else              { src = w2; kw = 3; jj = 2; }
    const int feat  = f * 16 + (lane & 15);
    const int cbase = kt * 32 + ((lane >> 4) << 3);
    __bf16* dst = Wpack + ((((nt * 4 + kt) << 6) + lane) << 3);
#pragma unroll
    for (int j = 0; j < 8; ++j)
      dst[j] = (__bf16)src[(feat * 128 + cbase + j) * kw + jj];
  } else {
    const int idx = (bid - 48) * 256 + t;          // 0..49151
    const int j = idx & 7, lane = (idx >> 3) & 63, rest = idx >> 9;  // 0..95
    const int kt = rest % 12, nt = rest / 12;
    const int o = nt * 16 + (lane & 15);
    const int q = kt * 32 + ((lane >> 4) << 3) + j;
    const float v = lw[o * 384 + q];
    const __bf16 hi = (__bf16)v;
    Lhi[idx] = hi;
    Llo[idx] = (__bf16)(v - (float)hi);
  }
}

// ---------------------------------------------------------------------------
// K2 (R0 version, best known: 144.7 us): fused conv + relu + ragged max.
// One block per segment.  Tap shifts via LDS A-row offsets (rows zero-padded
// through MT*16+1), so each pool accumulates directly.
// C/D layout (m89-verified): col = lane&15, row = (lane>>4)*4 + reg.
// ---------------------------------------------------------------------------
__global__ __launch_bounds__(256, 4)
void k_conv(const float* __restrict__ x, const int* __restrict__ sizes,
            const int* __restrict__ offsets,
            const float* __restrict__ cb0, const float* __restrict__ cb1,
            const float* __restrict__ cb2,
            const bf16x8* __restrict__ Wpack,
            __bf16* __restrict__ Phi, __bf16* __restrict__ Plo) {
  __shared__ __bf16 xh[66 * 136];   // [row][128 + 8 pad] bf16, 17.9 KB
  const int b = blockIdx.x;
  const int s = sizes[b];
  const long off = offsets[b];
  const int t = threadIdx.x;
  const int MT = (s + 15) >> 4;     // 1..4

  // ---- two-phase staging: 8 predicated float4 loads (all in flight),
  // then convert+store.  Covers rows [0, s). ----
  {
    const int quads = s << 5;       // s*128/4
    float4 v[8];
#pragma unroll
    for (int i = 0; i < 8; ++i) {
      const int qi = t + (i << 8);
      if (qi < quads) {
        const int r = qi >> 5, c = (qi & 31) << 2;
        v[i] = *(const float4*)(x + (off + r) * 128 + c);
      }
    }
#pragma unroll
    for (int i = 0; i < 8; ++i) {
      const int qi = t + (i << 8);
      if (qi < quads) {
        const int r = qi >> 5, c = (qi & 31) << 2;
        bf16x4 h; h[0] = (__bf16)v[i].x; h[1] = (__bf16)v[i].y;
                  h[2] = (__bf16)v[i].z; h[3] = (__bf16)v[i].w;
        *(bf16x4*)&xh[r * 136 + c] = h;
      }
    }
    // zero rows [s, MT*16+2): taps read up to row MT*16+1
    const int zend = MT * 16 + 2;
    const int c = (t & 31) << 2;
    for (int r = s + (t >> 5); r < zend; r += 8)
      *(bf16x4*)&xh[r * 136 + c] =
          bf16x4{(__bf16)0.f, (__bf16)0.f, (__bf16)0.f, (__bf16)0.f};
  }
  __syncthreads();

  const int wid = t >> 6, lane = t & 63;
  const int lo16 = lane & 15, g16 = lane >> 4;

#pragma unroll
  for (int fi = 0; fi < 2; ++fi) {
    const int ft = wid + (fi << 2);
    const int feat = ft * 16 + lo16;

    f32x4 acc[4][3];   // [mtile][pool]
#pragma unroll
    for (int mt = 0; mt < 4; ++mt)
#pragma unroll
      for (int p = 0; p < 3; ++p)
        acc[mt][p] = f32x4{0.f, 0.f, 0.f, 0.f};

#pragma unroll
    for (int kt = 0; kt < 4; ++kt) {
      // slices: 0=w1j0, 1=w2j0, 2=w2j1, 3=w3j0, 4=w3j1, 5=w3j2
      bf16x8 bf[6];
#pragma unroll
      for (int sl = 0; sl < 6; ++sl)
        bf[sl] = Wpack[(((sl * 8 + ft) * 4 + kt) << 6) + lane];
#pragma unroll
      for (int mt = 0; mt < 4; ++mt) {
        if (mt < MT) {   // uniform per block
          const __bf16* ap = &xh[(mt * 16 + lo16) * 136 + kt * 32 + (g16 << 3)];
          const bf16x8 A0 = *(const bf16x8*)ap;
          const bf16x8 A1 = *(const bf16x8*)(ap + 136);
          const bf16x8 A2 = *(const bf16x8*)(ap + 272);
          acc[mt][0] = MFMA16(A0, bf[0], acc[mt][0]);
          acc[mt][1] = MFMA16(A0, bf[1], acc[mt][1]);
          acc[mt][1] = MFMA16(A1, bf[2], acc[mt][1]);
          acc[mt][2] = MFMA16(A0, bf[3], acc[mt][2]);
          acc[mt][2] = MFMA16(A1, bf[4], acc[mt][2]);
          acc[mt][2] = MFMA16(A2, bf[5], acc[mt][2]);
        }
      }
    }

    // ---- epilogue: predicated max over valid rows, butterfly, store ----
    float m1 = -1e30f, m2 = -1e30f, m3 = -1e30f;
#pragma unroll
    for (int mt = 0; mt < 4; ++mt) {
      if (mt >= MT) continue;  // uniform
#pragma unroll
      for (int v = 0; v < 4; ++v) {
        const int lrow = mt * 16 + g16 * 4 + v;
        if (lrow < s)     m1 = fmaxf(m1, acc[mt][0][v]);
        if (lrow < s - 1) m2 = fmaxf(m2, acc[mt][1][v]);
        if (lrow < s - 2) m3 = fmaxf(m3, acc[mt][2][v]);
      }
    }
    m1 = fmaxf(m1, __shfl_xor(m1, 16)); m1 = fmaxf(m1, __shfl_xor(m1, 32));
    m2 = fmaxf(m2, __shfl_xor(m2, 16)); m2 = fmaxf(m2, __shfl_xor(m2, 32));
    m3 = fmaxf(m3, __shfl_xor(m3, 16)); m3 = fmaxf(m3, __shfl_xor(m3, 32));
    if (g16 == 0) {
      // max(relu(h)) == relu(max(Y)+b): bias row-constant, relu monotone
      const float p1 = fmaxf(m1 + cb0[feat], 0.f);
      const float p2 = fmaxf(m2 + cb1[feat], 0.f);
      const float p3 = fmaxf(m3 + cb2[feat], 0.f);
      const __bf16 h1 = (__bf16)p1, h2 = (__bf16)p2, h3 = (__bf16)p3;
      const long row = (long)b * 384;
      Phi[row + feat]       = h1;
      Plo[row + feat]       = (__bf16)(p1 - (float)h1);
      Phi[row + 128 + feat] = h2;
      Plo[row + 128 + feat] = (__bf16)(p2 - (float)h2);
      Phi[row + 256 + feat] = h3;
      Plo[row + 256 + feat] = (__bf16)(p3 - (float)h3);
    }
  }
}

// ---------------------------------------------------------------------------
// K3 v2: out = tanh(P[8192,384] @ lin_w^T + lin_b), split bf16 MFMA.
// Latency fixes vs v1: (a) 3 independent accumulator chains (dep chain
// 36 -> 12 MFMAs, 3-way ILP); (b) 1024 blocks: each block = 16 rows x 64
// feats (n-half), 4 blocks/CU.  Weight reads stay disjoint across n-halves;
// only P staging duplicates (x2 = +12 MB, negligible).
// ---------------------------------------------------------------------------
__global__ __launch_bounds__(256, 4)
void k_lin(const __bf16* __restrict__ Phi, const __bf16* __restrict__ Plo,
           const bf16x8* __restrict__ Lhi, const bf16x8* __restrict__ Llo,
           const float* __restrict__ lb, float* __restrict__ out) {
  __shared__ __bf16 ph[16 * 392];   // [row][384 + 8 pad]
  __shared__ __bf16 pl[16 * 392];
  const int blk = blockIdx.x, t = threadIdx.x;
  const int mb = blk >> 1, nh = blk & 1;
  const long rbase = (long)mb * 16;
#pragma unroll
  for (int i = 0; i < 3; ++i) {
    const int ci = t + (i << 8);
    const int r = ci / 48, cc = ci % 48;
    *(int4*)&ph[r * 392 + (cc << 3)] = *(const int4*)&Phi[(rbase + r) * 384 + (cc << 3)];
    *(int4*)&pl[r * 392 + (cc << 3)] = *(const int4*)&Plo[(rbase + r) * 384 + (cc << 3)];
  }
  __syncthreads();
  const int wid = t >> 6, lane = t & 63;
  const int lo16 = lane & 15, g = lane >> 4;
  const int nt = (nh << 2) + wid;       // global n-tile 0..7
  f32x4 ahh = f32x4{0.f, 0.f, 0.f, 0.f};
  f32x4 alh = f32x4{0.f, 0.f, 0.f, 0.f};
  f32x4 ahl = f32x4{0.f, 0.f, 0.f, 0.f};
#pragma unroll
  for (int kt = 0; kt < 12; ++kt) {
    const bf16x8 bh = Lhi[((nt * 12 + kt) << 6) + lane];
    const bf16x8 bl = Llo[((nt * 12 + kt) << 6) + lane];
    const int aoff = lo16 * 392 + kt * 32 + (g << 3);
    const bf16x8 ah = *(const bf16x8*)&ph[aoff];
    const bf16x8 al = *(const bf16x8*)&pl[aoff];
    ahh = MFMA16(ah, bh, ahh);
    alh = MFMA16(al, bh, alh);
    ahl = MFMA16(ah, bl, ahl);
  }
  const int o = (nt << 4) + lo16;
  const float bias = lb[o];
#pragma unroll
  for (int v = 0; v < 4; ++v) {
    const int r = g * 4 + v;
    const float val = ahh[v] + alh[v] + ahl[v] + bias;
    out[(rbase + r) * 128 + o] = 1.f - 2.f / (__expf(2.f * val) + 1.f);
  }
}

// ---------------------------------------------------------------------------
extern "C" void kernel_launch(void* const* d_in, const int* in_sizes, int n_in,
                              void* d_out, int out_size, void* d_ws, size_t ws_size,
                              hipStream_t stream) {
  const float* x   = (const float*)d_in[0];
  const int* sizes = (const int*)d_in[1];
  const float* w0  = (const float*)d_in[2];
  const float* cb0 = (const float*)d_in[3];
  const float* w1  = (const float*)d_in[4];
  const float* cb1 = (const float*)d_in[5];
  const float* w2  = (const float*)d_in[6];
  const float* cb2 = (const float*)d_in[7];
  const float* lw  = (const float*)d_in[8];
  const float* lb  = (const float*)d_in[9];

  char* ws = (char*)d_ws;
  size_t o = 0;
  int*    offsets = (int*)ws;                 o += 32768;
  __bf16* Wpack   = (__bf16*)(ws + o);        o += 196608;     // 48*4*64*8*2
  __bf16* Lhi     = (__bf16*)(ws + o);        o += 98304;      // 8*12*64*8*2
  __bf16* Llo     = (__bf16*)(ws + o);        o += 98304;
  __bf16* Phi     = (__bf16*)(ws + o);        o += 8192L * 384 * 2;
  __bf16* Plo     = (__bf16*)(ws + o);        o += 8192L * 384 * 2;

  k_prep<<<241, 256, 0, stream>>>(sizes, offsets, w0, w1, w2, lw, Wpack, Lhi, Llo);
  k_conv<<<8192, 256, 0, stream>>>(x, sizes, offsets, cb0, cb1, cb2,
                                   (const bf16x8*)Wpack, Phi, Plo);
  k_lin<<<1024, 256, 0, stream>>>(Phi, Plo, (const bf16x8*)Lhi,
                                  (const bf16x8*)Llo, lb, (float*)d_out);
}